// Round 13
// baseline (65.300 us; speedup 1.0000x reference)
//
#include <hip/hip_runtime.h>

// Quantized 3x3 conv, stride 1, pad 1 (pad value = input zero point 3).
// x: int32 [32][128][56][56] (values in int8 range)
// weight: int32 [256][128][3][3]
// bias: int32 [256]
// weight_scale: float [256]
// out: int32 [32][256][56][56] (quantized int8 values in int32 container)

#define NB    32
#define CIN   128
#define HH    56
#define WW    56
#define COUT  256
#define HP    58          // padded H
#define WP    58          // padded W
#define PIX   (HH*WW)     // 3136
#define KTOT  1152        // 9 * 128
#define NCHUNK 18         // K chunks of 64

#define NPT   28          // pixel tiles per batch (3136 = 28*112)
#define BN    112         // pixels per block
#define NJ    7           // B fragments per wave (112/16)
#define PHB1  (NJ*1024)   // one chunk of B in LDS: 7168 B; ring of 3

typedef int v4i __attribute__((ext_vector_type(4)));

#define GLOAD_LDS(gsrc, ldst) \
    __builtin_amdgcn_global_load_lds( \
        (const __attribute__((address_space(1))) void*)(gsrc), \
        (__attribute__((address_space(3))) void*)(ldst), 16, 0, 0)

// ---------------- Phase 1a: pack x (NCHW int32 -> padded NHWC int8) -------
// LDS-transpose: coalesced global reads (lanes = w) AND coalesced global
// writes (lanes = contiguous dwords). LDS u32 tile [56][33] (2-way alias,
// free). Borders filled inline; all threads reach the barrier.
__global__ void pack_x_kernel(const int* __restrict__ x,
                              unsigned char* __restrict__ xp8,
                              int n0) {
    int bx = blockIdx.x;
    int nl = bx / HP;
    int hp = bx % HP;
    int nb = n0 + nl;
    int tid = threadIdx.x;         // 256
    unsigned int* rowo = (unsigned int*)(xp8 + (size_t)(nl*HP + hp) * WP * CIN);

    if (hp == 0 || hp == HP-1) {   // full pad row: 1856 dwords
        const v4i zp = {0x03030303, 0x03030303, 0x03030303, 0x03030303};
        for (int i = tid; i < (WP*CIN)/16; i += 256)
            ((v4i*)rowo)[i] = zp;
        return;
    }

    __shared__ unsigned int lt[WW * 33];   // 56 x 33 dwords = 7392 B

    int h  = hp - 1;
    int wl = tid & 63;             // lane = w (0..55 active)
    int cg = tid >> 6;             // wave index = ci phase 0..3
    if (wl < WW) {
        const int s = HH*WW;
#pragma unroll
        for (int k = 0; k < 8; ++k) {
            int ci0 = cg*4 + k*16;
            const int* xb = x + (((size_t)(nb*CIN + ci0)*HH + h)*WW + wl);
            int v0 = xb[0], v1 = xb[s], v2 = xb[2*s], v3 = xb[3*s];
            unsigned int pack = (v0 & 0xFF) | ((v1 & 0xFF) << 8) |
                                ((v2 & 0xFF) << 16) | ((unsigned)(v3 & 0xFF) << 24);
            lt[wl*33 + (ci0 >> 2)] = pack;
        }
    }
    __syncthreads();

#pragma unroll
    for (int it = 0; it < 7; ++it) {
        int idx = it*256 + tid;
        int p = idx >> 5;          // pixel 0..55
        int d = idx & 31;          // dword within pixel
        rowo[(p + 1)*32 + d] = lt[p*33 + d];
    }
    if (tid < 64) {
        int off = (tid < 32) ? tid : ((WP-1)*32 + (tid - 32));
        rowo[off] = 0x03030303u;
    }
}

// ---------------- Phase 1b: pack weight into FRAGMENT order ----------------
// w8f[((t*16 + g)*16 + lr)*64 + (k&63)], t=k>>6 chunk, g=co>>4, lr=co&15,
// k = r*128 + ci (tap-major). A 16co-fragment = contiguous 1KB.
__global__ void pack_w_kernel(const int* __restrict__ wt,
                              unsigned char* __restrict__ w8f) {
    int co = blockIdx.x;           // 256
    int t  = threadIdx.x;          // 128
    for (int idx = t; idx < KTOT/4; idx += 128) {
        int k  = idx * 4;
        int r  = k >> 7;           // tap 0..8
        int ci = k & 127;
        const int* wb = wt + ((co*CIN + ci)*9 + r);
        int v0 = wb[0], v1 = wb[9], v2 = wb[18], v3 = wb[27];
        unsigned int pack = (v0 & 0xFF) | ((v1 & 0xFF) << 8) |
                            ((v2 & 0xFF) << 16) | ((unsigned)(v3 & 0xFF) << 24);
        int tch = k >> 6;
        size_t dst = ((size_t)((tch*16 + (co >> 4))*16 + (co & 15)))*64 + (k & 63);
        *(unsigned int*)(w8f + dst) = pack;
    }
}

__device__ __forceinline__ int koff_of(int t) {
    int r  = t >> 1;
    int kh = (r >= 6) ? 2 : (r >= 3 ? 1 : 0);
    int kw = r - kh*3;
    return ((kh*WP + kw) << 7) + ((t & 1) << 6);
}

// ---------------- Phase 2: 8-phase-style overlapped implicit GEMM ---------
// Grid: 2 co-halves * 28 pixel-tiles * nc batches. Block: 256 thr = 4 waves.
// Tile: 128co x 112px; wave wm owns co [ch*128+wm*32, +32) x 112px.
// Per chunk t (ONE barrier):
//   STAGE(t+2) -> ring[(t+2)%3]   (2 glds/wave, 2-deep prefetch)
//   a_nxt <- w8f chunk t+1        (2 glds)
//   vmcnt(4) [exactly the 4 ops younger than stage(t+1) -> sound]
//   s_barrier                     [all waves' stage(t+1) visible]
//   ds_read b_nxt <- ring[(t+1)%3]  (ISSUE ONLY - retires after MFMA)
//   setprio(1); 14 MFMA on (a_cur, b_cur); setprio(0)
//   lgkmcnt(0)+sched_barrier      [b_nxt in regs; slot freed pre-overwrite]
// Ring-of-3 WAR: slot rewritten >= 1 barrier + 1 full iter after its reads
// lgkm-retire -> race-free with a single barrier per chunk.
__launch_bounds__(256, 3)
__global__ void conv_kernel(const unsigned char* __restrict__ w8f,
                            const unsigned char* __restrict__ xp8,
                            const int* __restrict__ bias,
                            const float* __restrict__ wscale,
                            int* __restrict__ out,
                            int n0) {
    __shared__ __align__(16) unsigned char ldsB[3*PHB1];

    int bx = blockIdx.x;
    int ch = bx & 1;               // co-half (fastest-varying: pair shares B)
    int bxr = bx >> 1;
    int pt = bxr % NPT;
    int nl = bxr / NPT;
    int nb = n0 + nl;
    int p0 = pt * BN;

    int tid  = threadIdx.x;
    int lane = tid & 63;
    int wm   = tid >> 6;           // 0..3
    int lr   = lane & 15;
    int lg   = lane >> 4;

    // ---- B staging: slots s0,s1 per wave (16 px x 64B each) ----
    int l4 = lane >> 2;                              // row within 16-row group
    int sw = (lane & 3) ^ ((lane >> 3) & 3);         // swizzled data k-slot
    int s0 = wm*2;
    int s1 = (wm*2+1 > 6) ? 6 : wm*2+1;              // wave3 duplicates slot 6
    int s0u = __builtin_amdgcn_readfirstlane(s0);
    int s1u = __builtin_amdgcn_readfirstlane(s1);
    int pA = p0 + s0*16 + l4;
    int pB = p0 + s1*16 + l4;
    const unsigned char* bsrc0 =
        xp8 + ((size_t)((nl*HP + pA/WW)*WP + pA%WW))*CIN + sw*16;
    const unsigned char* bsrc1 =
        xp8 + ((size_t)((nl*HP + pB/WW)*WP + pB%WW))*CIN + sw*16;

    // ---- B fragment read address (swizzled) ----
    int rslot = lg ^ ((lr >> 1) & 3);
    int vb = lr*64 + rslot*16;                       // b[j] at vb + j*1024

    // ---- A fragment base: frag g = ch*8 + wm*2 + i (i=0,1), 1KB each ----
    const unsigned char* abase =
        w8f + (size_t)(ch*8 + wm*2)*1024 + (lr*64 + lg*16);

    v4i acc[2][NJ];
#pragma unroll
    for (int i = 0; i < 2; ++i)
#pragma unroll
        for (int j = 0; j < NJ; ++j)
            acc[i][j] = (v4i){0, 0, 0, 0};

#define STAGE1(T, ROFF) do {                                                   \
        int k_ = koff_of(T);                                                   \
        GLOAD_LDS(bsrc0 + k_, &ldsB[(ROFF) + s0u*1024]);                       \
        GLOAD_LDS(bsrc1 + k_, &ldsB[(ROFF) + s1u*1024]);                       \
    } while (0)

    v4i bA[NJ], bB[NJ], aA[2], aB[2];

    // ---- prologue: stage chunks 0,1; load a(0); read b(0) ----
    STAGE1(0, 0);
    STAGE1(1, PHB1);
#pragma unroll
    for (int i = 0; i < 2; ++i) aA[i] = *(const v4i*)(abase + i*1024);
    asm volatile("s_waitcnt vmcnt(4)" ::: "memory");   // stage(0) retired
    __builtin_amdgcn_sched_barrier(0);
    __builtin_amdgcn_s_barrier();
#pragma unroll
    for (int j = 0; j < NJ; ++j)
        bA[j] = *(const v4i*)&ldsB[vb + j*1024];
    asm volatile("s_waitcnt lgkmcnt(0)" ::: "memory");
    __builtin_amdgcn_sched_barrier(0);

#define ITER(T, BC, BNX, AC, ANX) do {                                         \
        if ((T) < NCHUNK-2) STAGE1((T)+2, (((T)+2)%3)*PHB1);                   \
        if ((T) < NCHUNK-1) {                                                  \
            _Pragma("unroll")                                                  \
            for (int i_ = 0; i_ < 2; ++i_)                                     \
                ANX[i_] = *(const v4i*)(abase + (size_t)((T)+1)*16384          \
                                        + i_*1024);                            \
            asm volatile("s_waitcnt vmcnt(4)" ::: "memory");                   \
        } else {                                                               \
            asm volatile("s_waitcnt vmcnt(0)" ::: "memory");                   \
        }                                                                      \
        __builtin_amdgcn_sched_barrier(0);                                     \
        __builtin_amdgcn_s_barrier();                                          \
        if ((T) < NCHUNK-1) {                                                  \
            int roff_ = (((T)+1)%3)*PHB1;                                      \
            _Pragma("unroll")                                                  \
            for (int j_ = 0; j_ < NJ; ++j_)                                    \
                BNX[j_] = *(const v4i*)&ldsB[roff_ + vb + j_*1024];            \
        }                                                                      \
        __builtin_amdgcn_s_setprio(1);                                         \
        _Pragma("unroll")                                                      \
        for (int i_ = 0; i_ < 2; ++i_)                                         \
            _Pragma("unroll")                                                  \
            for (int j_ = 0; j_ < NJ; ++j_)                                    \
                acc[i_][j_] = __builtin_amdgcn_mfma_i32_16x16x64_i8(           \
                    AC[i_], BC[j_], acc[i_][j_], 0, 0, 0);                     \
        __builtin_amdgcn_s_setprio(0);                                         \
        asm volatile("s_waitcnt lgkmcnt(0)" ::: "memory");                     \
        __builtin_amdgcn_sched_barrier(0);                                     \
    } while (0)

#pragma unroll
    for (int tt = 0; tt < NCHUNK/2; ++tt) {
        ITER(2*tt,   bA, bB, aA, aB);
        ITER(2*tt+1, bB, bA, aB, aA);
    }
#undef ITER
#undef STAGE1

    // Epilogue: q = clamp(rint((acc+bias) * (0.05*ws/0.1) + (-2)), -128, 127)
#pragma unroll
    for (int i = 0; i < 2; ++i) {
#pragma unroll
        for (int rr = 0; rr < 4; ++rr) {
            int co = ch*128 + wm*32 + i*16 + lg*4 + rr;
            float sc = __fdiv_rn(__fmul_rn(0.05f, wscale[co]), 0.1f);
            int bs = bias[co];
            int* orow = out + ((size_t)(nb*COUT + co))*PIX + p0;
#pragma unroll
            for (int j = 0; j < NJ; ++j) {
                float accf = (float)(acc[i][j][rr] + bs);
                float y = __fadd_rn(__fmul_rn(accf, sc), -2.0f);
                y = rintf(y);
                y = fminf(fmaxf(y, -128.0f), 127.0f);
                orow[j*16 + lr] = (int)y;
            }
        }
    }
}

// ---------------- Fallback: naive direct conv (only if ws too small) ------
__launch_bounds__(256)
__global__ void conv_direct_kernel(const int* __restrict__ x,
                                   const int* __restrict__ wt,
                                   const int* __restrict__ bias,
                                   const float* __restrict__ wscale,
                                   int* __restrict__ out) {
    size_t idx = (size_t)blockIdx.x * 256 + threadIdx.x;
    if (idx >= (size_t)NB * COUT * PIX) return;
    int w  = idx % WW;
    int h  = (idx / WW) % HH;
    int co = (idx / PIX) % COUT;
    int nb = idx / ((size_t)PIX * COUT);
    int acc = 0;
    for (int ci = 0; ci < CIN; ++ci) {
        const int* xb = x + ((size_t)(nb*CIN + ci)*HH)*WW;
        const int* wb = wt + ((size_t)(co*CIN + ci)*9);
        for (int kh = 0; kh < 3; ++kh) {
            int hh = h + kh - 1;
            for (int kw = 0; kw < 3; ++kw) {
                int ww2 = w + kw - 1;
                int xv = (hh >= 0 && hh < HH && ww2 >= 0 && ww2 < WW)
                         ? xb[hh*WW + ww2] : 3;
                acc += xv * wb[kh*3 + kw];
            }
        }
    }
    float sc = __fdiv_rn(__fmul_rn(0.05f, wscale[co]), 0.1f);
    float y = __fadd_rn(__fmul_rn((float)(acc + bias[co]), sc), -2.0f);
    y = rintf(y);
    y = fminf(fmaxf(y, -128.0f), 127.0f);
    out[idx] = (int)y;
}

extern "C" void kernel_launch(void* const* d_in, const int* in_sizes, int n_in,
                              void* d_out, int out_size, void* d_ws, size_t ws_size,
                              hipStream_t stream) {
    const int*   x      = (const int*)d_in[0];
    const int*   weight = (const int*)d_in[1];
    const int*   bias   = (const int*)d_in[2];
    const float* wscale = (const float*)d_in[3];
    int*         out    = (int*)d_out;

    const size_t XOFF = 320u << 10;                  // w8f region: 288KB used
    const size_t BPB  = (size_t)HP * WP * CIN;       // 430,592 B per batch
    const size_t SLAB = (size_t)COUT * PIX * 4;      // 3,211,264 B out per batch

    size_t navail = (ws_size > XOFF) ? (ws_size - XOFF) / BPB : 0;

    unsigned char* w8f = (unsigned char*)d_ws;
    unsigned char* xpw = (unsigned char*)d_ws + XOFF;

    if (navail >= 4) {
        // Two-pass d_out-scratch scheme: Na batches staged in d_out's tail,
        // wsN batches in d_ws. (With the observed ~411MB d_ws, Na==0 and
        // this is a single pack_x + single conv.)
        int wsN = (int)(navail < 32 ? navail : 32);
        int Na  = 32 - wsN;        // 0..28
        unsigned char* xpt = (unsigned char*)d_out + (size_t)Na * SLAB;

        pack_w_kernel<<<dim3(COUT), dim3(128), 0, stream>>>(weight, w8f);
        if (Na > 0)
            pack_x_kernel<<<dim3(Na*HP), dim3(256), 0, stream>>>(x, xpt, 0);
        pack_x_kernel<<<dim3(wsN*HP), dim3(256), 0, stream>>>(x, xpw, Na);
        if (Na > 0)
            conv_kernel<<<dim3(2*NPT*Na), dim3(256), 0, stream>>>(
                w8f, xpt, bias, wscale, out, 0);
        conv_kernel<<<dim3(2*NPT*wsN), dim3(256), 0, stream>>>(
            w8f, xpw, bias, wscale, out, Na);
    } else if (navail >= 1) {
        // Old chunked scheme for tiny workspaces.
        int nchk = navail >= 2 ? 2 : 1;
        pack_w_kernel<<<dim3(COUT), dim3(128), 0, stream>>>(weight, w8f);
        for (int n0 = 0; n0 < NB; n0 += nchk) {
            int nc = (NB - n0 < nchk) ? (NB - n0) : nchk;
            pack_x_kernel<<<dim3(nc*HP), dim3(256), 0, stream>>>(x, xpw, n0);
            conv_kernel<<<dim3(2*NPT*nc), dim3(256), 0, stream>>>(
                w8f, xpw, bias, wscale, out, n0);
        }
    } else {
        size_t total = (size_t)NB * COUT * PIX;
        conv_direct_kernel<<<dim3((total + 255) / 256), dim3(256), 0, stream>>>(
            x, weight, bias, wscale, out);
    }
}

// Round 14
// 58.979 us; speedup vs baseline: 1.1072x; 1.1072x over previous
//
#include <hip/hip_runtime.h>

// Quantized 3x3 conv, stride 1, pad 1 (pad value = input zero point 3).
// x: int32 [32][128][56][56] (values in int8 range)
// weight: int32 [256][128][3][3]
// bias: int32 [256]
// weight_scale: float [256]
// out: int32 [32][256][56][56] (quantized int8 values in int32 container)

#define NB    32
#define CIN   128
#define HH    56
#define WW    56
#define COUT  256
#define HP    58          // padded H
#define WP    58          // padded W
#define PIX   (HH*WW)     // 3136
#define KTOT  1152        // 9 * 128
#define NCHUNK 18         // K chunks of 64

#define NPT   28          // pixel tiles per batch (3136 = 28*112)
#define BN    112         // pixels per block
#define NJ    7           // B fragments per wave (112/16)
#define PHB1  (NJ*1024)   // one chunk of B in LDS: 7168 B; ring of 3

typedef int v4i __attribute__((ext_vector_type(4)));

#define GLOAD_LDS(gsrc, ldst) \
    __builtin_amdgcn_global_load_lds( \
        (const __attribute__((address_space(1))) void*)(gsrc), \
        (__attribute__((address_space(3))) void*)(ldst), 16, 0, 0)

// ---------------- Phase 1: merged pack (weight + x) -----------------------
// blocks [0,256): pack weight into fragment order.
// blocks [256, 256+nc*HP): pack x NCHW -> padded NHWC int8 (LDS transpose).
__global__ void pack_both_kernel(const int* __restrict__ x,
                                 unsigned char* __restrict__ xp8,
                                 const int* __restrict__ wt,
                                 unsigned char* __restrict__ w8f,
                                 int n0) {
    __shared__ unsigned int lt[WW * 33];   // 56 x 33 dwords = 7392 B
    int bx = blockIdx.x;
    int tid = threadIdx.x;         // 256

    if (bx < COUT) {
        // ---- pack_w: w8f[((t*16+g)*16+lr)*64 + (k&63)], k = tap*128+ci ----
        int co = bx;
        for (int idx = tid; idx < KTOT/4; idx += 256) {
            int k  = idx * 4;
            int r  = k >> 7;           // tap 0..8
            int ci = k & 127;
            const int* wb = wt + ((co*CIN + ci)*9 + r);
            int v0 = wb[0], v1 = wb[9], v2 = wb[18], v3 = wb[27];
            unsigned int pack = (v0 & 0xFF) | ((v1 & 0xFF) << 8) |
                                ((v2 & 0xFF) << 16) | ((unsigned)(v3 & 0xFF) << 24);
            int tch = k >> 6;
            size_t dst = ((size_t)((tch*16 + (co >> 4))*16 + (co & 15)))*64 + (k & 63);
            *(unsigned int*)(w8f + dst) = pack;
        }
        return;
    }

    int bxx = bx - COUT;
    int nl = bxx / HP;
    int hp = bxx % HP;
    int nb = n0 + nl;
    unsigned int* rowo = (unsigned int*)(xp8 + (size_t)(nl*HP + hp) * WP * CIN);

    if (hp == 0 || hp == HP-1) {   // full pad row: 1856 dwords
        const v4i zp = {0x03030303, 0x03030303, 0x03030303, 0x03030303};
        for (int i = tid; i < (WP*CIN)/16; i += 256)
            ((v4i*)rowo)[i] = zp;
        return;
    }

    int h  = hp - 1;
    int wl = tid & 63;             // lane = w (0..55 active)
    int cg = tid >> 6;             // wave index = ci phase 0..3
    if (wl < WW) {
        const int s = HH*WW;
#pragma unroll
        for (int k = 0; k < 8; ++k) {
            int ci0 = cg*4 + k*16;
            const int* xb = x + (((size_t)(nb*CIN + ci0)*HH + h)*WW + wl);
            int v0 = xb[0], v1 = xb[s], v2 = xb[2*s], v3 = xb[3*s];
            unsigned int pack = (v0 & 0xFF) | ((v1 & 0xFF) << 8) |
                                ((v2 & 0xFF) << 16) | ((unsigned)(v3 & 0xFF) << 24);
            lt[wl*33 + (ci0 >> 2)] = pack;
        }
    }
    __syncthreads();

#pragma unroll
    for (int it = 0; it < 7; ++it) {
        int idx = it*256 + tid;
        int p = idx >> 5;          // pixel 0..55
        int d = idx & 31;          // dword within pixel
        rowo[(p + 1)*32 + d] = lt[p*33 + d];
    }
    if (tid < 64) {
        int off = (tid < 32) ? tid : ((WP-1)*32 + (tid - 32));
        rowo[off] = 0x03030303u;
    }
}

__device__ __forceinline__ int koff_of(int t) {
    int r  = t >> 1;
    int kh = (r >= 6) ? 2 : (r >= 3 ? 1 : 0);
    int kw = r - kh*3;
    return ((kh*WP + kw) << 7) + ((t & 1) << 6);
}

// ---------------- Phase 2: 8-wave BM=256 ring-buffered implicit GEMM ------
// Grid: 28 pixel-tiles * nc batches (bijective XCD swizzle). Block: 512 thr
// = 8 waves. Tile: 256co x 112px; wave w owns co [w*32, w*32+32) x 112px.
// acc[2][7] = 56 AGPR; lean body targets <=128 VGPR -> 4 waves/SIMD
// (16 waves/CU, 2 blocks). B staged ONCE per 256co: waves 0-6 stage slot w,
// wave 7 duplicates slot 6 (same data, benign) -> uniform 3 VMEM/iter/wave.
// Ring-of-3, ONE barrier per chunk; per-wave-sound vmcnt:
//   ops younger than own stage(p): a(p-1)x2 + stage(p+1) + a(p)x2 = 5
//   (p=0: 3 total younger; p=17: no stage(18) -> 4).
__launch_bounds__(512, 4)
__global__ void conv_kernel(const unsigned char* __restrict__ w8f,
                            const unsigned char* __restrict__ xp8,
                            const int* __restrict__ bias,
                            const float* __restrict__ wscale,
                            int* __restrict__ out,
                            int n0) {
    __shared__ __align__(16) unsigned char ldsB[3*PHB1];

    // Bijective XCD swizzle (m204): XCD x gets a contiguous chunk of tiles.
    int nwg = gridDim.x;
    int bx0 = blockIdx.x;
    int q = nwg >> 3, r = nwg & 7;
    int xcd = bx0 & 7, idx8 = bx0 >> 3;
    int bx = (xcd < r ? xcd*(q+1) : r*(q+1) + (xcd-r)*q) + idx8;

    int pt = bx % NPT;
    int nl = bx / NPT;
    int nb = n0 + nl;
    int p0 = pt * BN;

    int tid  = threadIdx.x;
    int lane = tid & 63;
    int wm   = tid >> 6;           // 0..7
    int lr   = lane & 15;
    int lg   = lane >> 4;

    // ---- B staging: wave w stages slot (w<7 ? w : 6), 16px x 64B ----
    int l4 = lane >> 2;                              // row within 16-row group
    int sw = (lane & 3) ^ ((lane >> 3) & 3);         // swizzled data k-slot
    int slot = (wm < 7) ? wm : 6;
    int slotu = __builtin_amdgcn_readfirstlane(slot);
    int pS = p0 + slot*16 + l4;
    const unsigned char* bsrc =
        xp8 + ((size_t)((nl*HP + pS/WW)*WP + pS%WW))*CIN + sw*16;

    // ---- B fragment read address (swizzled) ----
    int rslot = lg ^ ((lr >> 1) & 3);
    int vb = lr*64 + rslot*16;                       // b[j] at vb + j*1024

    // ---- A fragment base: frag g = wm*2 + i (i=0,1), 1KB each ----
    const unsigned char* abase =
        w8f + (size_t)(wm*2)*1024 + (lr*64 + lg*16);

    v4i acc[2][NJ];
#pragma unroll
    for (int i = 0; i < 2; ++i)
#pragma unroll
        for (int j = 0; j < NJ; ++j)
            acc[i][j] = (v4i){0, 0, 0, 0};

#define STAGE1(T) \
    GLOAD_LDS(bsrc + koff_of(T), &ldsB[((T)%3)*PHB1 + slotu*1024])

    // prologue: stage chunk 0 into ring slot 0
    STAGE1(0);

#pragma unroll
    for (int p = 0; p < NCHUNK; ++p) {
        if (p < NCHUNK-1) STAGE1(p+1);

        v4i a_[2];
#pragma unroll
        for (int i = 0; i < 2; ++i)
            a_[i] = *(const v4i*)(abase + (size_t)p*16384 + i*1024);

        if (p == 0)             asm volatile("s_waitcnt vmcnt(3)" ::: "memory");
        else if (p == NCHUNK-1) asm volatile("s_waitcnt vmcnt(4)" ::: "memory");
        else                    asm volatile("s_waitcnt vmcnt(5)" ::: "memory");
        __builtin_amdgcn_sched_barrier(0);
        __builtin_amdgcn_s_barrier();      // all waves' chunk-p B in LDS

        int roff = (p % 3) * PHB1;
        v4i b_[NJ];
#pragma unroll
        for (int j = 0; j < NJ; ++j)
            b_[j] = *(const v4i*)&ldsB[roff + vb + j*1024];
#pragma unroll
        for (int i = 0; i < 2; ++i)
#pragma unroll
            for (int j = 0; j < NJ; ++j)
                acc[i][j] = __builtin_amdgcn_mfma_i32_16x16x64_i8(
                    a_[i], b_[j], acc[i][j], 0, 0, 0);
        // no trailing barrier: ring-of-3 + post-barrier stage issue is
        // race-free (slot (p+1)%3 last read at iter p-2; those reads retired
        // before their MFMAs, which precede barrier(p-1), which precedes
        // this wave's STAGE(p+1) issue).
    }
#undef STAGE1

    // Epilogue: q = clamp(rint((acc+bias) * (0.05*ws/0.1) + (-2)), -128, 127)
#pragma unroll
    for (int i = 0; i < 2; ++i) {
#pragma unroll
        for (int rr = 0; rr < 4; ++rr) {
            int co = wm*32 + i*16 + lg*4 + rr;
            float sc = __fdiv_rn(__fmul_rn(0.05f, wscale[co]), 0.1f);
            int bs = bias[co];
            int* orow = out + ((size_t)(nb*COUT + co))*PIX + p0;
#pragma unroll
            for (int j = 0; j < NJ; ++j) {
                float accf = (float)(acc[i][j][rr] + bs);
                float y = __fadd_rn(__fmul_rn(accf, sc), -2.0f);
                y = rintf(y);
                y = fminf(fmaxf(y, -128.0f), 127.0f);
                orow[j*16 + lr] = (int)y;
            }
        }
    }
}

// ---------------- Fallback: naive direct conv (only if ws too small) ------
__launch_bounds__(256)
__global__ void conv_direct_kernel(const int* __restrict__ x,
                                   const int* __restrict__ wt,
                                   const int* __restrict__ bias,
                                   const float* __restrict__ wscale,
                                   int* __restrict__ out) {
    size_t idx = (size_t)blockIdx.x * 256 + threadIdx.x;
    if (idx >= (size_t)NB * COUT * PIX) return;
    int w  = idx % WW;
    int h  = (idx / WW) % HH;
    int co = (idx / PIX) % COUT;
    int nb = idx / ((size_t)PIX * COUT);
    int acc = 0;
    for (int ci = 0; ci < CIN; ++ci) {
        const int* xb = x + ((size_t)(nb*CIN + ci)*HH)*WW;
        const int* wb = wt + ((size_t)(co*CIN + ci)*9);
        for (int kh = 0; kh < 3; ++kh) {
            int hh = h + kh - 1;
            for (int kw = 0; kw < 3; ++kw) {
                int ww2 = w + kw - 1;
                int xv = (hh >= 0 && hh < HH && ww2 >= 0 && ww2 < WW)
                         ? xb[hh*WW + ww2] : 3;
                acc += xv * wb[kh*3 + kw];
            }
        }
    }
    float sc = __fdiv_rn(__fmul_rn(0.05f, wscale[co]), 0.1f);
    float y = __fadd_rn(__fmul_rn((float)(acc + bias[co]), sc), -2.0f);
    y = rintf(y);
    y = fminf(fmaxf(y, -128.0f), 127.0f);
    out[idx] = (int)y;
}

extern "C" void kernel_launch(void* const* d_in, const int* in_sizes, int n_in,
                              void* d_out, int out_size, void* d_ws, size_t ws_size,
                              hipStream_t stream) {
    const int*   x      = (const int*)d_in[0];
    const int*   weight = (const int*)d_in[1];
    const int*   bias   = (const int*)d_in[2];
    const float* wscale = (const float*)d_in[3];
    int*         out    = (int*)d_out;

    const size_t XOFF = 320u << 10;                  // w8f region: 288KB used
    const size_t BPB  = (size_t)HP * WP * CIN;       // 430,592 B per batch
    const size_t SLAB = (size_t)COUT * PIX * 4;      // 3,211,264 B out per batch

    size_t navail = (ws_size > XOFF) ? (ws_size - XOFF) / BPB : 0;

    unsigned char* w8f = (unsigned char*)d_ws;
    unsigned char* xpw = (unsigned char*)d_ws + XOFF;

    if (navail >= 4) {
        // Two-pass d_out-scratch scheme: Na batches staged in d_out's tail,
        // wsN batches in d_ws. (With the observed ~411MB d_ws, Na==0 and
        // this is a single pack + single conv.)
        int wsN = (int)(navail < 32 ? navail : 32);
        int Na  = 32 - wsN;        // 0..28
        unsigned char* xpt = (unsigned char*)d_out + (size_t)Na * SLAB;

        if (Na > 0) {
            pack_both_kernel<<<dim3(COUT + Na*HP), dim3(256), 0, stream>>>(
                x, xpt, weight, w8f, 0);
            pack_both_kernel<<<dim3(COUT + wsN*HP), dim3(256), 0, stream>>>(
                x, xpw, weight, w8f, Na);
            conv_kernel<<<dim3(NPT*Na), dim3(512), 0, stream>>>(
                w8f, xpt, bias, wscale, out, 0);
            conv_kernel<<<dim3(NPT*wsN), dim3(512), 0, stream>>>(
                w8f, xpw, bias, wscale, out, Na);
        } else {
            pack_both_kernel<<<dim3(COUT + 32*HP), dim3(256), 0, stream>>>(
                x, xpw, weight, w8f, 0);
            conv_kernel<<<dim3(NPT*32), dim3(512), 0, stream>>>(
                w8f, xpw, bias, wscale, out, 0);
        }
    } else if (navail >= 1) {
        // Chunked scheme for tiny workspaces.
        int nchk = navail >= 2 ? 2 : 1;
        for (int n0 = 0; n0 < NB; n0 += nchk) {
            int nc = (NB - n0 < nchk) ? (NB - n0) : nchk;
            pack_both_kernel<<<dim3(COUT + nc*HP), dim3(256), 0, stream>>>(
                x, xpw, weight, w8f, n0);
            conv_kernel<<<dim3(NPT*nc), dim3(512), 0, stream>>>(
                w8f, xpw, bias, wscale, out, n0);
        }
    } else {
        size_t total = (size_t)NB * COUT * PIX;
        conv_direct_kernel<<<dim3((total + 255) / 256), dim3(256), 0, stream>>>(
            x, weight, bias, wscale, out);
    }
}

// Round 15
// 58.100 us; speedup vs baseline: 1.1239x; 1.0151x over previous
//
#include <hip/hip_runtime.h>

// Quantized 3x3 conv, stride 1, pad 1 (pad value = input zero point 3).
// x: int32 [32][128][56][56] (values in int8 range)
// weight: int32 [256][128][3][3]
// bias: int32 [256]
// weight_scale: float [256]
// out: int32 [32][256][56][56] (quantized int8 values in int32 container)

#define NB    32
#define CIN   128
#define HH    56
#define WW    56
#define COUT  256
#define HP    58          // padded H
#define WP    58          // padded W
#define PIX   (HH*WW)     // 3136
#define KTOT  1152        // 9 * 128
#define NCHUNK 18         // K chunks of 64

#define NPT   28          // pixel tiles per batch (3136 = 28*112)
#define BN    112         // pixels per block
#define NJ    7           // B fragments per wave (112/16)
#define PHB1  (NJ*1024)   // one chunk of B in LDS: 7168 B; ring of 3
#define PL    (HP*WP*64)  // xp8 plane stride: 215296 B (ci 0-63 / 64-127)
#define BPB   (2*PL)      // 430592 B per batch slab

typedef int v4i __attribute__((ext_vector_type(4)));

#define GLOAD_LDS(gsrc, ldst) \
    __builtin_amdgcn_global_load_lds( \
        (const __attribute__((address_space(1))) void*)(gsrc), \
        (__attribute__((address_space(3))) void*)(ldst), 16, 0, 0)

// ---------------- Phase 1: merged pack (weight + x) -----------------------
// blocks [0,256): pack weight into fragment order.
// blocks [256, 256+nc*HP): pack x NCHW -> padded two-plane NHWC int8:
//   xp8[nl][q][hp*WP+wp][64], q = ci>>6. Dense 64B per (pixel, chunk-parity).
__global__ void pack_both_kernel(const int* __restrict__ x,
                                 unsigned char* __restrict__ xp8,
                                 const int* __restrict__ wt,
                                 unsigned char* __restrict__ w8f,
                                 int n0) {
    __shared__ unsigned int lt[WW * 33];   // 56 x 33 dwords = 7392 B
    int bx = blockIdx.x;
    int tid = threadIdx.x;         // 256

    if (bx < COUT) {
        // ---- pack_w: w8f[((t*16+g)*16+lr)*64 + (k&63)], k = tap*128+ci ----
        int co = bx;
        for (int idx = tid; idx < KTOT/4; idx += 256) {
            int k  = idx * 4;
            int r  = k >> 7;           // tap 0..8
            int ci = k & 127;
            const int* wb = wt + ((co*CIN + ci)*9 + r);
            int v0 = wb[0], v1 = wb[9], v2 = wb[18], v3 = wb[27];
            unsigned int pack = (v0 & 0xFF) | ((v1 & 0xFF) << 8) |
                                ((v2 & 0xFF) << 16) | ((unsigned)(v3 & 0xFF) << 24);
            int tch = k >> 6;
            size_t dst = ((size_t)((tch*16 + (co >> 4))*16 + (co & 15)))*64 + (k & 63);
            *(unsigned int*)(w8f + dst) = pack;
        }
        return;
    }

    int bxx = bx - COUT;
    int nl = bxx / HP;
    int hp = bxx % HP;
    int nb = n0 + nl;
    unsigned char* slab = xp8 + (size_t)nl * BPB;
    unsigned int* q0 = (unsigned int*)(slab + (size_t)hp * WP * 64);
    unsigned int* q1 = (unsigned int*)(slab + PL + (size_t)hp * WP * 64);

    if (hp == 0 || hp == HP-1) {   // full pad row: WP*64 B per plane
        const v4i zp = {0x03030303, 0x03030303, 0x03030303, 0x03030303};
        v4i* a0 = (v4i*)q0;
        v4i* a1 = (v4i*)q1;
        for (int i = tid; i < (WP*64)/16; i += 256) { a0[i] = zp; a1[i] = zp; }
        return;
    }

    int h  = hp - 1;
    int wl = tid & 63;             // lane = w (0..55 active)
    int cg = tid >> 6;             // wave index = ci phase 0..3
    if (wl < WW) {
        const int s = HH*WW;
#pragma unroll
        for (int k = 0; k < 8; ++k) {
            int ci0 = cg*4 + k*16;
            const int* xb = x + (((size_t)(nb*CIN + ci0)*HH + h)*WW + wl);
            int v0 = xb[0], v1 = xb[s], v2 = xb[2*s], v3 = xb[3*s];
            unsigned int pack = (v0 & 0xFF) | ((v1 & 0xFF) << 8) |
                                ((v2 & 0xFF) << 16) | ((unsigned)(v3 & 0xFF) << 24);
            lt[wl*33 + (ci0 >> 2)] = pack;
        }
    }
    __syncthreads();

    // stream out interior: 56 px x 32 dwords (16 per plane), lane-contiguous
#pragma unroll
    for (int it = 0; it < 7; ++it) {
        int idx = it*256 + tid;
        int p = idx >> 5;          // pixel 0..55
        int d = idx & 31;          // dword: 0-15 plane0, 16-31 plane1
        unsigned int* qq = (d < 16) ? q0 : q1;
        qq[(p + 1)*16 + (d & 15)] = lt[p*33 + d];
    }
    // border columns wp==0 and wp==57, both planes (16 dwords each)
    if (tid < 64) {
        int d = tid & 15;
        unsigned int* qq = (tid & 16) ? q1 : q0;
        int col = (tid & 32) ? (WP-1) : 0;
        qq[col*16 + d] = 0x03030303u;
    }
}

__device__ __forceinline__ int koff_of(int t) {
    int r  = t >> 1;
    int kh = (r >= 6) ? 2 : (r >= 3 ? 1 : 0);
    int kw = r - kh*3;
    return (t & 1) * PL + ((kh*WP + kw) << 6);
}

// ---------------- Phase 2: 8-wave BM=256 ring-buffered implicit GEMM ------
// Grid: 28 pixel-tiles * nc batches (bijective XCD swizzle). Block: 512 thr
// = 8 waves. Tile: 256co x 112px; wave w owns co [w*32, w*32+32) x 112px.
// ISSUE ORDER per chunk: a-loads(p) FIRST, then STAGE(p+1) (sched-fenced) —
// so the compiler's wait for a0(p) does NOT retire the fresh stage(p+1)
// (in-order vmcnt). Sound barrier wait: queue = stage(p),a0,a1,stage(p+1)
// -> vmcnt(3) retires stage(p) exactly (last iter: vmcnt(2)).
// B staged ONCE per 256co (waves 0-6 stage slot w, wave 7 dups slot 6).
// Ring-of-3, ONE barrier per chunk. setprio(1) around the MFMA cluster.
__launch_bounds__(512, 4)
__global__ void conv_kernel(const unsigned char* __restrict__ w8f,
                            const unsigned char* __restrict__ xp8,
                            const int* __restrict__ bias,
                            const float* __restrict__ wscale,
                            int* __restrict__ out,
                            int n0) {
    __shared__ __align__(16) unsigned char ldsB[3*PHB1];

    // Bijective XCD swizzle (m204): XCD x gets a contiguous chunk of tiles.
    int nwg = gridDim.x;
    int bx0 = blockIdx.x;
    int q = nwg >> 3, r = nwg & 7;
    int xcd = bx0 & 7, idx8 = bx0 >> 3;
    int bx = (xcd < r ? xcd*(q+1) : r*(q+1) + (xcd-r)*q) + idx8;

    int pt = bx % NPT;
    int nl = bx / NPT;
    int nb = n0 + nl;
    int p0 = pt * BN;

    int tid  = threadIdx.x;
    int lane = tid & 63;
    int wm   = tid >> 6;           // 0..7
    int lr   = lane & 15;
    int lg   = lane >> 4;

    // ---- B staging: wave w stages slot (w<7 ? w : 6), 16px x 64B ----
    int l4 = lane >> 2;                              // row within 16-row group
    int sw = (lane & 3) ^ ((lane >> 3) & 3);         // swizzled data k-slot
    int slot = (wm < 7) ? wm : 6;
    int slotu = __builtin_amdgcn_readfirstlane(slot);
    int pS = p0 + slot*16 + l4;
    int ph = pS / WW, pw = pS % WW;
    const unsigned char* bsrc =
        xp8 + (size_t)nl*BPB + ((size_t)(ph*WP + pw))*64 + sw*16;

    // ---- B fragment read address (swizzled) ----
    int rslot = lg ^ ((lr >> 1) & 3);
    int vb = lr*64 + rslot*16;                       // b[j] at vb + j*1024

    // ---- A fragment base: frag g = wm*2 + i (i=0,1), 1KB each ----
    const unsigned char* abase =
        w8f + (size_t)(wm*2)*1024 + (lr*64 + lg*16);

    v4i acc[2][NJ];
#pragma unroll
    for (int i = 0; i < 2; ++i)
#pragma unroll
        for (int j = 0; j < NJ; ++j)
            acc[i][j] = (v4i){0, 0, 0, 0};

#define STAGE1(T) \
    GLOAD_LDS(bsrc + koff_of(T), &ldsB[((T)%3)*PHB1 + slotu*1024])

    // prologue: stage chunk 0 into ring slot 0
    STAGE1(0);

#pragma unroll
    for (int p = 0; p < NCHUNK; ++p) {
        // A-loads FIRST (so their waits don't drain the fresh stage)
        v4i a_[2];
#pragma unroll
        for (int i = 0; i < 2; ++i)
            a_[i] = *(const v4i*)(abase + (size_t)p*16384 + i*1024);
        __builtin_amdgcn_sched_barrier(0);
        if (p < NCHUNK-1) STAGE1(p+1);

        if (p < NCHUNK-1) asm volatile("s_waitcnt vmcnt(3)" ::: "memory");
        else              asm volatile("s_waitcnt vmcnt(2)" ::: "memory");
        __builtin_amdgcn_sched_barrier(0);
        __builtin_amdgcn_s_barrier();      // all waves' chunk-p B in LDS

        int roff = (p % 3) * PHB1;
        v4i b_[NJ];
#pragma unroll
        for (int j = 0; j < NJ; ++j)
            b_[j] = *(const v4i*)&ldsB[roff + vb + j*1024];
        __builtin_amdgcn_s_setprio(1);
#pragma unroll
        for (int i = 0; i < 2; ++i)
#pragma unroll
            for (int j = 0; j < NJ; ++j)
                acc[i][j] = __builtin_amdgcn_mfma_i32_16x16x64_i8(
                    a_[i], b_[j], acc[i][j], 0, 0, 0);
        __builtin_amdgcn_s_setprio(0);
        // no trailing barrier: ring-of-3 + post-barrier stage issue is
        // race-free (slot (p+1)%3 last read at iter p-2; those reads retired
        // before their MFMAs, which precede barrier(p-1), which precedes
        // this wave's STAGE(p+1) issue).
    }
#undef STAGE1

    // Epilogue: q = clamp(rint((acc+bias) * (0.05*ws/0.1) + (-2)), -128, 127)
#pragma unroll
    for (int i = 0; i < 2; ++i) {
#pragma unroll
        for (int rr = 0; rr < 4; ++rr) {
            int co = wm*32 + i*16 + lg*4 + rr;
            float sc = __fdiv_rn(__fmul_rn(0.05f, wscale[co]), 0.1f);
            int bs = bias[co];
            int* orow = out + ((size_t)(nb*COUT + co))*PIX + p0;
#pragma unroll
            for (int j = 0; j < NJ; ++j) {
                float accf = (float)(acc[i][j][rr] + bs);
                float y = __fadd_rn(__fmul_rn(accf, sc), -2.0f);
                y = rintf(y);
                y = fminf(fmaxf(y, -128.0f), 127.0f);
                orow[j*16 + lr] = (int)y;
            }
        }
    }
}

// ---------------- Fallback: naive direct conv (only if ws too small) ------
__launch_bounds__(256)
__global__ void conv_direct_kernel(const int* __restrict__ x,
                                   const int* __restrict__ wt,
                                   const int* __restrict__ bias,
                                   const float* __restrict__ wscale,
                                   int* __restrict__ out) {
    size_t idx = (size_t)blockIdx.x * 256 + threadIdx.x;
    if (idx >= (size_t)NB * COUT * PIX) return;
    int w  = idx % WW;
    int h  = (idx / WW) % HH;
    int co = (idx / PIX) % COUT;
    int nb = idx / ((size_t)PIX * COUT);
    int acc = 0;
    for (int ci = 0; ci < CIN; ++ci) {
        const int* xb = x + ((size_t)(nb*CIN + ci)*HH)*WW;
        const int* wb = wt + ((size_t)(co*CIN + ci)*9);
        for (int kh = 0; kh < 3; ++kh) {
            int hh = h + kh - 1;
            for (int kw = 0; kw < 3; ++kw) {
                int ww2 = w + kw - 1;
                int xv = (hh >= 0 && hh < HH && ww2 >= 0 && ww2 < WW)
                         ? xb[hh*WW + ww2] : 3;
                acc += xv * wb[kh*3 + kw];
            }
        }
    }
    float sc = __fdiv_rn(__fmul_rn(0.05f, wscale[co]), 0.1f);
    float y = __fadd_rn(__fmul_rn((float)(acc + bias[co]), sc), -2.0f);
    y = rintf(y);
    y = fminf(fmaxf(y, -128.0f), 127.0f);
    out[idx] = (int)y;
}

extern "C" void kernel_launch(void* const* d_in, const int* in_sizes, int n_in,
                              void* d_out, int out_size, void* d_ws, size_t ws_size,
                              hipStream_t stream) {
    const int*   x      = (const int*)d_in[0];
    const int*   weight = (const int*)d_in[1];
    const int*   bias   = (const int*)d_in[2];
    const float* wscale = (const float*)d_in[3];
    int*         out    = (int*)d_out;

    const size_t XOFF = 320u << 10;                  // w8f region: 288KB used
    const size_t SLAB = (size_t)COUT * PIX * 4;      // 3,211,264 B out per batch

    size_t navail = (ws_size > XOFF) ? (ws_size - XOFF) / BPB : 0;

    unsigned char* w8f = (unsigned char*)d_ws;
    unsigned char* xpw = (unsigned char*)d_ws + XOFF;

    if (navail >= 4) {
        // Two-pass d_out-scratch scheme: Na batches staged in d_out's tail,
        // wsN batches in d_ws. (With the observed ~411MB d_ws, Na==0 and
        // this is a single pack + single conv.)
        int wsN = (int)(navail < 32 ? navail : 32);
        int Na  = 32 - wsN;        // 0..28
        unsigned char* xpt = (unsigned char*)d_out + (size_t)Na * SLAB;

        if (Na > 0) {
            pack_both_kernel<<<dim3(COUT + Na*HP), dim3(256), 0, stream>>>(
                x, xpt, weight, w8f, 0);
            pack_both_kernel<<<dim3(COUT + wsN*HP), dim3(256), 0, stream>>>(
                x, xpw, weight, w8f, Na);
            conv_kernel<<<dim3(NPT*Na), dim3(512), 0, stream>>>(
                w8f, xpt, bias, wscale, out, 0);
            conv_kernel<<<dim3(NPT*wsN), dim3(512), 0, stream>>>(
                w8f, xpw, bias, wscale, out, Na);
        } else {
            pack_both_kernel<<<dim3(COUT + 32*HP), dim3(256), 0, stream>>>(
                x, xpw, weight, w8f, 0);
            conv_kernel<<<dim3(NPT*32), dim3(512), 0, stream>>>(
                w8f, xpw, bias, wscale, out, 0);
        }
    } else if (navail >= 1) {
        // Chunked scheme for tiny workspaces.
        int nchk = navail >= 2 ? 2 : 1;
        for (int n0 = 0; n0 < NB; n0 += nchk) {
            int nc = (NB - n0 < nchk) ? (NB - n0) : nchk;
            pack_both_kernel<<<dim3(COUT + nc*HP), dim3(256), 0, stream>>>(
                x, xpw, weight, w8f, n0);
            conv_kernel<<<dim3(NPT*nc), dim3(512), 0, stream>>>(
                w8f, xpw, bias, wscale, out, n0);
        }
    } else {
        size_t total = (size_t)NB * COUT * PIX;
        conv_direct_kernel<<<dim3((total + 255) / 256), dim3(256), 0, stream>>>(
            x, weight, bias, wscale, out);
    }
}